// Round 1
// baseline (8974.549 us; speedup 1.0000x reference)
//
#include <hip/hip_runtime.h>
#include <hip/hip_bf16.h>

// LSTM: N=64, T=1024, D=512, H=512. out (N,T,H) fp32 = h_{t+1} for t=0..T-1.
//
// Design: persistent kernel, 128 wgs x 256 thr (one per CU, all resident).
//   grid = 32 col-groups (16 h-cols each) x 4 row-groups (16 batch rows each).
//   Each wave (4/wg) owns one gate's 16 a-cols, K=1024 ([x_t | h_t]) with
//   fp16 B-fragments persistent in 128 VGPRs. A staged to LDS per step.
//   Row-groups are independent sync domains (32 wgs each): monotonic
//   arrival counter in ws, release fence + atomicAdd / relaxed spin + acquire.
//   h ring buffer (2 slots) in ws as fp16; c-state in one VGPR per thread.

#define TT 1024
#define NB 64
#define DD 512
#define HH 512
#define LROW 1032  // 1024 K elems + 8 pad (breaks power-of-2 LDS stride)

typedef _Float16 half8 __attribute__((ext_vector_type(8)));
typedef _Float16 half4 __attribute__((ext_vector_type(4)));
typedef float floatx4 __attribute__((ext_vector_type(4)));

__global__ void init_ws_kernel(int* done) {
    done[threadIdx.x] = 0;  // 256 ints covers 4 row-group counters (stride 64)
}

__global__ __launch_bounds__(256, 1) void lstm_persist(
    const float* __restrict__ x, const float* __restrict__ h0,
    const float* __restrict__ Wx, const float* __restrict__ Wh,
    const float* __restrict__ b, float* __restrict__ out,
    _Float16* __restrict__ hbuf, int* __restrict__ done)
{
    const int tid  = threadIdx.x;
    const int lane = tid & 63;
    const int wave = tid >> 6;          // 0..3 = gate (i,f,o,g)
    const int cg   = blockIdx.x & 31;   // column group: h-cols cg*16..+15
    const int rg   = blockIdx.x >> 5;   // row group: batch rows rg*16..+15
    const int row0 = rg << 4;

    __shared__ _Float16 xh[16 * LROW];     // A tile: 16 rows x (512 x | 512 h)
    __shared__ float    gatebuf[4 * 272];  // 4 gates x (16 rows x 17 padded)

    // ---- persistent B fragments: this wave's 16 a-cols, full K=1024 ----
    // B[k][n]: n = lane&15, k = kt*32 + (lane>>4)*8 + j
    const int bcol = (wave << 9) + (cg << 4) + (lane & 15);
    const int kq   = (lane >> 4) << 3;
    half8 bfrag[32];
#pragma unroll
    for (int kt = 0; kt < 16; ++kt) {      // K 0..511 : Wx
#pragma unroll
        for (int j = 0; j < 8; ++j) {
            int k = (kt << 5) + kq + j;
            bfrag[kt][j] = (_Float16)Wx[(size_t)k * 2048 + bcol];
        }
    }
#pragma unroll
    for (int kt = 16; kt < 32; ++kt) {     // K 512..1023 : Wh
#pragma unroll
        for (int j = 0; j < 8; ++j) {
            int k = (kt << 5) + kq + j - 512;
            bfrag[kt][j] = (_Float16)Wh[(size_t)k * 2048 + bcol];
        }
    }

    // ---- epilogue mapping: thread <-> (row, col) of the 16x16 h tile ----
    const int tr = tid >> 4;
    const int tc = tid & 15;
    const int gn = row0 + tr;         // global batch row
    const int gh = (cg << 4) + tc;    // global h col
    const float bi = b[0 * 512 + gh];
    const float bf = b[1 * 512 + gh];
    const float bo = b[2 * 512 + gh];
    const float bg = b[3 * 512 + gh];
    float c_state = 0.f;

    int* dptr = done + (rg << 6);     // 256B-spaced counter per row-group

    const int r2 = tid >> 7;          // 0..1 : row parity for staging
    const int d4 = tid & 127;         // vec4 index within a 512-elem row
    const int arow = (lane & 15) * LROW + kq;   // A-frag base (elems)

    for (int t = 0; t < TT; ++t) {
        // ---- stage x_t rows (K 0..511), fp32 -> fp16 (independent of h) ----
#pragma unroll
        for (int i = 0; i < 8; ++i) {
            int r = (i << 1) + r2;
            const float* xrow = x + (size_t)(row0 + r) * (TT * DD) + (size_t)t * DD;
            float4 xv = ((const float4*)xrow)[d4];
            half4 hv;
            hv.x = (_Float16)xv.x; hv.y = (_Float16)xv.y;
            hv.z = (_Float16)xv.z; hv.w = (_Float16)xv.w;
            *(half4*)&xh[r * LROW + (d4 << 2)] = hv;
        }

        // ---- wait for h_t (all 32 wgs of this row-group done with step t-1) ----
        if (t > 0) {
            if (tid == 0) {
                const int target = t << 5;
                while (__hip_atomic_load(dptr, __ATOMIC_RELAXED,
                                         __HIP_MEMORY_SCOPE_AGENT) < target) { }
                __threadfence();   // acquire: invalidate stale cached h
            }
            __syncthreads();
            // ---- stage h_t rows (K 512..1023) from ring buffer ----
            const _Float16* hsrc = hbuf + (size_t)(t & 1) * (NB * HH);
#pragma unroll
            for (int i = 0; i < 8; ++i) {
                int r = (i << 1) + r2;
                half4 hv = ((const half4*)(hsrc + (size_t)(row0 + r) * HH))[d4];
                *(half4*)&xh[r * LROW + 512 + (d4 << 2)] = hv;
            }
        } else {
            // h_0 from input (fp32 -> fp16)
#pragma unroll
            for (int i = 0; i < 8; ++i) {
                int r = (i << 1) + r2;
                const float* hrow = h0 + (size_t)(row0 + r) * HH;
                float4 xv = ((const float4*)hrow)[d4];
                half4 hv;
                hv.x = (_Float16)xv.x; hv.y = (_Float16)xv.y;
                hv.z = (_Float16)xv.z; hv.w = (_Float16)xv.w;
                *(half4*)&xh[r * LROW + 512 + (d4 << 2)] = hv;
            }
        }
        __syncthreads();

        // ---- MFMA: 16 rows x 16 cols, K=1024, two independent chains ----
        floatx4 acc0 = {0.f, 0.f, 0.f, 0.f};
        floatx4 acc1 = {0.f, 0.f, 0.f, 0.f};
#pragma unroll
        for (int kt = 0; kt < 32; kt += 2) {
            half8 a0 = *(const half8*)&xh[arow + (kt << 5)];
            half8 a1 = *(const half8*)&xh[arow + ((kt + 1) << 5)];
            acc0 = __builtin_amdgcn_mfma_f32_16x16x32_f16(a0, bfrag[kt],     acc0, 0, 0, 0);
            acc1 = __builtin_amdgcn_mfma_f32_16x16x32_f16(a1, bfrag[kt + 1], acc1, 0, 0, 0);
        }
        floatx4 acc = acc0 + acc1;

        // ---- exchange gates through LDS: C/D layout col=lane&15, row=quad*4+v ----
        {
            const int ccol = lane & 15;
            const int crow = (lane >> 4) << 2;
#pragma unroll
            for (int v = 0; v < 4; ++v)
                gatebuf[wave * 272 + (crow + v) * 17 + ccol] = acc[v];
        }
        __syncthreads();

        // ---- elementwise LSTM cell, write out (fp32) + h ring (fp16) ----
        {
            const int gidx = tr * 17 + tc;
            float ai = gatebuf[0 * 272 + gidx] + bi;
            float af = gatebuf[1 * 272 + gidx] + bf;
            float ao = gatebuf[2 * 272 + gidx] + bo;
            float ag = gatebuf[3 * 272 + gidx] + bg;
            float ig = 1.f / (1.f + __expf(-ai));
            float fg = 1.f / (1.f + __expf(-af));
            float og = 1.f / (1.f + __expf(-ao));
            float gg = 2.f / (1.f + __expf(-2.f * ag)) - 1.f;   // tanh
            c_state = fg * c_state + ig * gg;
            float hv = og * (2.f / (1.f + __expf(-2.f * c_state)) - 1.f);
            out[(size_t)gn * (TT * HH) + (size_t)t * HH + gh] = hv;
            hbuf[(size_t)((t + 1) & 1) * (NB * HH) + (size_t)gn * HH + gh] = (_Float16)hv;
        }

        // ---- arrive: all stores drained (syncthreads waits vmcnt(0)), then
        //      release fence + device-scope increment ----
        __syncthreads();
        if (tid == 0) {
            __threadfence();
            atomicAdd(dptr, 1);
        }
    }
}

extern "C" void kernel_launch(void* const* d_in, const int* in_sizes, int n_in,
                              void* d_out, int out_size, void* d_ws, size_t ws_size,
                              hipStream_t stream) {
    const float* x  = (const float*)d_in[0];
    const float* h0 = (const float*)d_in[1];
    const float* Wx = (const float*)d_in[2];
    const float* Wh = (const float*)d_in[3];
    const float* b  = (const float*)d_in[4];
    float* out = (float*)d_out;

    _Float16* hbuf = (_Float16*)d_ws;                       // 2*64*512 fp16 = 128 KB
    int* done = (int*)((char*)d_ws + 2 * NB * HH * sizeof(_Float16));

    init_ws_kernel<<<1, 256, 0, stream>>>(done);
    lstm_persist<<<dim3(128), dim3(256), 0, stream>>>(x, h0, Wx, Wh, b, out, hbuf, done);
}